// Round 2
// baseline (4111.879 us; speedup 1.0000x reference)
//
#include <hip/hip_runtime.h>
#include <cstdint>
#include <cstddef>

// LSTM: BS=64, H=512, T=256.  gates = [x_t, h] @ [U;V] + bias, K=1024.
// out = hidden_seq (64,512,256) fp32 | h_T (64,512) | c_T (64,512)

typedef _Float16 f16;
typedef _Float16 f16x8 __attribute__((ext_vector_type(8)));
typedef float f32x4 __attribute__((ext_vector_type(4)));

#define BS 64
#define H  512
#define TSTEPS 256
#define KTOT 1024
#define N_BLOCKS 64
#define HSLOT (BS * H)          // 32768 elems per hbuf time-slot

// ---- static device scratch: no d_ws dependence, no overflow risk ----
__device__ f16 g_W16T[(size_t)4 * H * KTOT];          // 4 MB: W^T[col][k]
__device__ f16 g_xT[(size_t)TSTEPS * HSLOT];          // 16 MB: x time-major fp16
__device__ f16 g_hbuf[(size_t)(TSTEPS + 1) * HSLOT];  // 16.8 MB: h per step
__device__ int g_counters[512];

// ---------------- prep: zero hbuf[0] + sync counters ----------------
__global__ void prep_zero() {
  int i = blockIdx.x * 256 + threadIdx.x;
  if (i < HSLOT) g_hbuf[i] = (f16)0.f;
  if (i < 512) g_counters[i] = 0;
}

// ---- prep: W16T[col][k] = (k<512 ? U[k][col] : V[k-512][col]) as fp16 ----
__global__ void build_w16t(const float* __restrict__ U, const float* __restrict__ V) {
  __shared__ float tile[32][33];
  int colT = blockIdx.x;            // 0..63
  int kT   = blockIdx.y;            // 0..31
  int x = threadIdx.x & 31, y = threadIdx.x >> 5;
  int col0 = colT * 32, k0 = kT * 32;
  for (int yy = y; yy < 32; yy += 8) {
    int k = k0 + yy;
    float v = (k < H) ? U[(size_t)k * 2048 + col0 + x]
                      : V[(size_t)(k - H) * 2048 + col0 + x];
    tile[yy][x] = v;
  }
  __syncthreads();
  for (int yy = y; yy < 32; yy += 8)
    g_W16T[(size_t)(col0 + yy) * KTOT + k0 + x] = (f16)tile[x][yy];
}

// ---------------- prep: xT16[t][b][k] = x[b][k][t] as fp16 ----------------
__global__ void build_xt16(const float* __restrict__ x) {
  __shared__ float tile[32][33];
  int kt = blockIdx.x;              // 0..15
  int tt = blockIdx.y;              // 0..7
  int b  = blockIdx.z;              // 0..63
  int xl = threadIdx.x & 31, y = threadIdx.x >> 5;
  int k0 = kt * 32, t0 = tt * 32;
  for (int yy = y; yy < 32; yy += 8)
    tile[yy][xl] = x[(size_t)b * (H * TSTEPS) + (size_t)(k0 + yy) * TSTEPS + t0 + xl];
  __syncthreads();
  for (int yy = y; yy < 32; yy += 8)
    g_xT[((size_t)(t0 + yy) * BS + b) * H + k0 + xl] = (f16)tile[xl][yy];
}

// ---------------- persistent recurrent kernel ----------------
// 64 blocks x 256 threads. bg = blockIdx&1 (32 batch rows), bc = blockIdx>>1
// (16 hidden units, all 4 gates). 4 waves = 2 row-groups x 2 K-halves.
// K-half 0 = x@U (k 0..511), K-half 1 = h@V (k 512..1023).
__launch_bounds__(256, 1)
__global__ void lstm_rec(const float* __restrict__ bias, float* __restrict__ out_cT) {
  __shared__ float red[2][4][256];   // [row-group][gate][lane*4+i]

  const int tid  = threadIdx.x;
  const int lane = tid & 63;
  const int wv   = tid >> 6;        // 0..3
  const int r    = wv >> 1;         // row-group 0..1
  const int kh   = wv & 1;          // K-half
  const int bg   = blockIdx.x & 1;
  const int bc   = blockIdx.x >> 1; // 0..31
  const int b_base = bg * 32 + r * 16;
  const int l16 = lane & 15;
  const int lk8 = (lane >> 4) * 8;

  // A fragment base: row = b_base + (lane&15), k = (lane>>4)*8 + ...
  const size_t aoff = (size_t)(b_base + l16) * H + lk8;
  // B fragment bases per gate: W16T[(g*512 + bc*16 + l16)][kh*512 + lk8 + ...]
  size_t boff[4];
  for (int g = 0; g < 4; ++g)
    boff[g] = (size_t)(g * H + bc * 16 + l16) * KTOT + kh * H + lk8;

  float bgt[4];
  for (int g = 0; g < 4; ++g) bgt[g] = bias[g * H + bc * 16 + l16];

  float c4[4] = {0.f, 0.f, 0.f, 0.f};

  for (int t = 0; t < TSTEPS; ++t) {
    f32x4 acc[4] = {};
    const f16* Aptr = (kh == 0) ? (g_xT + (size_t)t * HSLOT + aoff)
                                : (g_hbuf + (size_t)t * HSLOT + aoff);
    #pragma unroll 4
    for (int ki = 0; ki < 16; ++ki) {
      f16x8 a = *(const f16x8*)(Aptr + ki * 32);
      #pragma unroll
      for (int g = 0; g < 4; ++g) {
        f16x8 bb = *(const f16x8*)(g_W16T + boff[g] + ki * 32);
        acc[g] = __builtin_amdgcn_mfma_f32_16x16x32_f16(a, bb, acc[g], 0, 0, 0);
      }
    }

    if (kh == 1) {            // h-half writes partials to LDS
      #pragma unroll
      for (int g = 0; g < 4; ++g)
        *(f32x4*)&red[r][g][lane * 4] = acc[g];
    }
    __syncthreads();

    if (kh == 0) {            // x-half waves: reduce + nonlinearity + h store
      #pragma unroll
      for (int i = 0; i < 4; ++i) {
        float gi = acc[0][i] + red[r][0][lane * 4 + i] + bgt[0];
        float gf = acc[1][i] + red[r][1][lane * 4 + i] + bgt[1];
        float gg = acc[2][i] + red[r][2][lane * 4 + i] + bgt[2];
        float go = acc[3][i] + red[r][3][lane * 4 + i] + bgt[3];
        float it = 1.f / (1.f + __expf(-gi));
        float ft = 1.f / (1.f + __expf(-gf));
        float gt = tanhf(gg);
        float ot = 1.f / (1.f + __expf(-go));
        float c  = ft * c4[i] + it * gt;
        c4[i] = c;
        float hh = ot * tanhf(c);
        int b = b_base + (lane >> 4) * 4 + i;   // C/D: row=(lane>>4)*4+i
        int j = bc * 16 + l16;                  //      col=lane&15
        g_hbuf[(size_t)(t + 1) * HSLOT + (size_t)b * H + j] = (f16)hh;
        if (t == TSTEPS - 1)
          out_cT[(size_t)b * H + j] = c;
      }
    }

    // ---- grid sync ----
    __syncthreads();   // drains vmcnt: h stores complete in writer L2
    if (tid == 0) {
      // release: flushes writer L2 dirty lines to IC, then bump counter
      __hip_atomic_fetch_add(&g_counters[t], 1, __ATOMIC_RELEASE,
                             __HIP_MEMORY_SCOPE_AGENT);
      int spin = 0;
      while (__hip_atomic_load(&g_counters[t], __ATOMIC_RELAXED,
                               __HIP_MEMORY_SCOPE_AGENT) < N_BLOCKS) {
        if (++spin > 65536) break;          // safety hatch: no dead container
        __builtin_amdgcn_s_sleep(2);
      }
    }
    __syncthreads();
    // acquire: invalidate L1+L2 so next step's h loads see remote writes
    __builtin_amdgcn_fence(__ATOMIC_ACQUIRE, "agent");
  }
}

// ---------------- finalize: out[b][j][t] = hbuf[t+1][b][j] ----------------
__global__ void finalize_seq(float* __restrict__ out) {
  __shared__ float tile[32][33];
  int jt = blockIdx.x;              // 0..15
  int tt = blockIdx.y;              // 0..7
  int b  = blockIdx.z;              // 0..63
  int xl = threadIdx.x & 31, y = threadIdx.x >> 5;
  int j0 = jt * 32, t0 = tt * 32;
  for (int yy = y; yy < 32; yy += 8)
    tile[yy][xl] = (float)g_hbuf[(size_t)(t0 + yy + 1) * HSLOT + (size_t)b * H + j0 + xl];
  __syncthreads();
  for (int yy = y; yy < 32; yy += 8)
    out[(size_t)b * (H * TSTEPS) + (size_t)(j0 + yy) * TSTEPS + t0 + xl] = tile[xl][yy];
}

__global__ void copy_hT(float* __restrict__ out_hT) {
  int i = blockIdx.x * 256 + threadIdx.x;
  if (i < HSLOT) out_hT[i] = (float)g_hbuf[(size_t)TSTEPS * HSLOT + i];
}

// ---------------- host ----------------
extern "C" void kernel_launch(void* const* d_in, const int* in_sizes, int n_in,
                              void* d_out, int out_size, void* d_ws, size_t ws_size,
                              hipStream_t stream) {
  (void)in_sizes; (void)n_in; (void)d_ws; (void)ws_size; (void)out_size;
  const float* x    = (const float*)d_in[0];
  const float* U    = (const float*)d_in[1];
  const float* V    = (const float*)d_in[2];
  const float* bias = (const float*)d_in[3];
  float* out = (float*)d_out;

  float* out_hT = out + (size_t)BS * H * TSTEPS;          // 8388608
  float* out_cT = out_hT + (size_t)BS * H;                // 8421376

  prep_zero<<<dim3(129), dim3(256), 0, stream>>>();
  build_w16t<<<dim3(64, 32), dim3(256), 0, stream>>>(U, V);
  build_xt16<<<dim3(16, 8, 64), dim3(256), 0, stream>>>(x);
  lstm_rec<<<dim3(N_BLOCKS), dim3(256), 0, stream>>>(bias, out_cT);
  finalize_seq<<<dim3(16, 8, 64), dim3(256), 0, stream>>>(out);
  copy_hT<<<dim3(128), dim3(256), 0, stream>>>(out_hT);
}

// Round 4
// 3275.946 us; speedup vs baseline: 1.2552x; 1.2552x over previous
//
#include <hip/hip_runtime.h>
#include <cstdint>
#include <cstddef>

// LSTM: BS=64, H=512, T=256.
// Round 3: XU = x@U + bias precomputed for all t (parallel GEMM);
// recurrent kernel: gates = XU[t] + h@V; per-group (32-block) flag barrier,
// no RMW contention.

typedef _Float16 f16;
typedef _Float16 f16x8 __attribute__((ext_vector_type(8)));
typedef float f32x4 __attribute__((ext_vector_type(4)));

#define BS 64
#define H  512
#define TSTEPS 256
#define KTOT 1024
#define N_BLOCKS 64
#define HSLOT (BS * H)          // 32768 elems per hbuf time-slot
#define GCOLS 2048              // 4*H gate columns

// ---- static device scratch ----
__device__ f16  g_W16T[(size_t)GCOLS * KTOT];          // 4 MB: W^T[col][k], k<512=U, k>=512=V
__device__ f16  g_xT[(size_t)TSTEPS * HSLOT];          // 16 MB: xT[t][b][k] fp16
__device__ f16  g_hbuf[(size_t)(TSTEPS + 1) * HSLOT];  // 16.8 MB
__device__ float g_XU[(size_t)TSTEPS * BS * GCOLS];    // 128 MB: x@U + bias, fp32
__device__ int  g_flags[2][64];                        // per-group epoch flags

// ---------------- prep: zero hbuf[0] + flags ----------------
__global__ void prep_zero() {
  int i = blockIdx.x * 256 + threadIdx.x;
  if (i < HSLOT) g_hbuf[i] = (f16)0.f;
  if (i < 128) ((int*)g_flags)[i] = 0;
}

// ---- prep: W16T[col][k] = (k<512 ? U[k][col] : V[k-512][col]) as fp16 ----
__global__ void build_w16t(const float* __restrict__ U, const float* __restrict__ V) {
  __shared__ float tile[32][33];
  int colT = blockIdx.x;            // 0..63
  int kT   = blockIdx.y;            // 0..31
  int x = threadIdx.x & 31, y = threadIdx.x >> 5;
  int col0 = colT * 32, k0 = kT * 32;
  for (int yy = y; yy < 32; yy += 8) {
    int k = k0 + yy;
    float v = (k < H) ? U[(size_t)k * GCOLS + col0 + x]
                      : V[(size_t)(k - H) * GCOLS + col0 + x];
    tile[yy][x] = v;
  }
  __syncthreads();
  for (int yy = y; yy < 32; yy += 8)
    g_W16T[(size_t)(col0 + yy) * KTOT + k0 + x] = (f16)tile[x][yy];
}

// ---------------- prep: xT16[t][b][k] = x[b][k][t] as fp16 ----------------
__global__ void build_xt16(const float* __restrict__ x) {
  __shared__ float tile[32][33];
  int kt = blockIdx.x;              // 0..15
  int tt = blockIdx.y;              // 0..7
  int b  = blockIdx.z;              // 0..63
  int xl = threadIdx.x & 31, y = threadIdx.x >> 5;
  int k0 = kt * 32, t0 = tt * 32;
  for (int yy = y; yy < 32; yy += 8)
    tile[yy][xl] = x[(size_t)b * (H * TSTEPS) + (size_t)(k0 + yy) * TSTEPS + t0 + xl];
  __syncthreads();
  for (int yy = y; yy < 32; yy += 8)
    g_xT[((size_t)(t0 + yy) * BS + b) * H + k0 + xl] = (f16)tile[xl][yy];
}

// ---------------- XU GEMM: g_XU[m][n] = xT[m][:512] @ U[:,n] + bias[n] ----
// m = t*BS + b (16384 rows), n = gate col (2048). Grid (512, 64), 4 waves,
// each wave one 16x16 C tile, K=512.
__global__ void xu_gemm(const float* __restrict__ bias) {
  const int tid  = threadIdx.x;
  const int lane = tid & 63;
  const int wv   = tid >> 6;
  const int l16  = lane & 15;
  const int lk8  = (lane >> 4) * 8;
  const int m0 = blockIdx.x * 32 + (wv >> 1) * 16;
  const int n0 = blockIdx.y * 32 + (wv & 1) * 16;

  const f16* Ap = g_xT   + (size_t)(m0 + l16) * H    + lk8;
  const f16* Bp = g_W16T + (size_t)(n0 + l16) * KTOT + lk8;
  f32x4 acc = {};
  #pragma unroll
  for (int ki = 0; ki < 16; ++ki) {
    f16x8 a = *(const f16x8*)(Ap + ki * 32);
    f16x8 b = *(const f16x8*)(Bp + ki * 32);
    acc = __builtin_amdgcn_mfma_f32_16x16x32_f16(a, b, acc, 0, 0, 0);
  }
  float bv = bias[n0 + l16];
  #pragma unroll
  for (int i = 0; i < 4; ++i) {
    int m = m0 + (lane >> 4) * 4 + i;     // C/D: row=(lane>>4)*4+i, col=lane&15
    g_XU[(size_t)m * GCOLS + n0 + l16] = acc[i] + bv;
  }
}

// ---------------- persistent recurrent kernel ----------------
// 64 blocks x 256 threads, two INDEPENDENT groups by bg = blockIdx&1.
// Block (bg,bc): rows bg*32..+32, gate cols {g*512 + bc*16..+16}.
// 4 waves = 2 row-subgroups x 2 K-halves of V's K=512.
__launch_bounds__(256, 1)
__global__ void lstm_rec(float* __restrict__ out_cT) {
  __shared__ float red[2][4][256];   // [row-subgroup][gate][lane*4+i]

  const int tid  = threadIdx.x;
  const int lane = tid & 63;
  const int wv   = tid >> 6;        // 0..3
  const int r    = wv >> 1;         // row-subgroup 0..1
  const int kh   = wv & 1;          // K-half of 512
  const int bg   = blockIdx.x & 1;
  const int bc   = blockIdx.x >> 1; // 0..31
  const int b_base = bg * 32 + r * 16;
  const int l16 = lane & 15;
  const int lk8 = (lane >> 4) * 8;

  // A-frag base: h[t] row = b_base + l16, k = kh*256 + lk8 + ki*32
  const size_t aoff = (size_t)(b_base + l16) * H + kh * 256 + lk8;
  // B (V) frag bases: W16T[(g*512 + bc*16 + l16)][512 + kh*256 + lk8 + ki*32]
  size_t boff[4];
  #pragma unroll
  for (int g = 0; g < 4; ++g)
    boff[g] = (size_t)(g * H + bc * 16 + l16) * KTOT + H + kh * 256 + lk8;

  float c4[4] = {0.f, 0.f, 0.f, 0.f};

  for (int t = 0; t < TSTEPS; ++t) {
    // --- XU prefetch (independent of h[t]; latency hides under the poll) ---
    float xu[4][4];                 // [gate][i]
    if (kh == 0) {
      #pragma unroll
      for (int i = 0; i < 4; ++i) {
        int row = b_base + (lane >> 4) * 4 + i;
        size_t xb = ((size_t)t * BS + row) * GCOLS + bc * 16 + l16;
        #pragma unroll
        for (int g = 0; g < 4; ++g) xu[g][i] = g_XU[xb + (size_t)g * H];
      }
    }

    // --- wait for h[t] (producers set flags = t after writing hbuf[t]) ---
    if (t > 0) {
      if (wv == 0) {
        int spin = 0;
        bool done;
        do {
          int v = (lane < 32)
            ? __hip_atomic_load(&g_flags[bg][lane], __ATOMIC_RELAXED,
                                __HIP_MEMORY_SCOPE_AGENT)
            : t;
          done = __all(v >= t);
          if (!done) {
            if (++spin > (1 << 17)) break;   // safety hatch
            __builtin_amdgcn_s_sleep(2);
          }
        } while (!done);
      }
      __syncthreads();
      // invalidate stale h lines (round-2-proven protocol)
      __builtin_amdgcn_fence(__ATOMIC_ACQUIRE, "agent");
    }

    // --- h[t] @ V ---
    f32x4 acc[4] = {};
    const f16* Ap = g_hbuf + (size_t)t * HSLOT + aoff;
    #pragma unroll
    for (int ki = 0; ki < 8; ++ki) {
      f16x8 a = *(const f16x8*)(Ap + ki * 32);
      #pragma unroll
      for (int g = 0; g < 4; ++g) {
        f16x8 bb = *(const f16x8*)(g_W16T + boff[g] + ki * 32);
        acc[g] = __builtin_amdgcn_mfma_f32_16x16x32_f16(a, bb, acc[g], 0, 0, 0);
      }
    }

    if (kh == 1) {
      #pragma unroll
      for (int g = 0; g < 4; ++g)
        *(f32x4*)&red[r][g][lane * 4] = acc[g];
    }
    __syncthreads();

    if (kh == 0) {                  // reduce + nonlinearity + h store
      #pragma unroll
      for (int i = 0; i < 4; ++i) {
        float gi = acc[0][i] + red[r][0][lane * 4 + i] + xu[0][i];
        float gf = acc[1][i] + red[r][1][lane * 4 + i] + xu[1][i];
        float gg = acc[2][i] + red[r][2][lane * 4 + i] + xu[2][i];
        float go = acc[3][i] + red[r][3][lane * 4 + i] + xu[3][i];
        float it = 1.f / (1.f + __expf(-gi));
        float ft = 1.f / (1.f + __expf(-gf));
        float gt = tanhf(gg);
        float ot = 1.f / (1.f + __expf(-go));
        float c  = ft * c4[i] + it * gt;
        c4[i] = c;
        float hh = ot * tanhf(c);
        int b = b_base + (lane >> 4) * 4 + i;   // C/D: row=(lane>>4)*4+i
        int j = bc * 16 + l16;                  //      col=lane&15
        g_hbuf[(size_t)(t + 1) * HSLOT + (size_t)b * H + j] = (f16)hh;
        if (t == TSTEPS - 1)
          out_cT[(size_t)b * H + j] = c;
      }
    }

    // --- arrive: release store (flushes this block's h to IC), no RMW ---
    __syncthreads();                // all waves' stores drained (vmcnt0 @ barrier)
    if (tid == 0)
      __hip_atomic_store(&g_flags[bg][bc], t + 1, __ATOMIC_RELEASE,
                         __HIP_MEMORY_SCOPE_AGENT);
  }
}

// ---------------- finalize: out[b][j][t] = hbuf[t+1][b][j] ----------------
__global__ void finalize_seq(float* __restrict__ out) {
  __shared__ float tile[32][33];
  int jt = blockIdx.x;              // 0..15
  int tt = blockIdx.y;              // 0..7
  int b  = blockIdx.z;              // 0..63
  int xl = threadIdx.x & 31, y = threadIdx.x >> 5;
  int j0 = jt * 32, t0 = tt * 32;
  for (int yy = y; yy < 32; yy += 8)
    tile[yy][xl] = (float)g_hbuf[(size_t)(t0 + yy + 1) * HSLOT + (size_t)b * H + j0 + xl];
  __syncthreads();
  for (int yy = y; yy < 32; yy += 8)
    out[(size_t)b * (H * TSTEPS) + (size_t)(j0 + yy) * TSTEPS + t0 + xl] = tile[xl][yy];
}

__global__ void copy_hT(float* __restrict__ out_hT) {
  int i = blockIdx.x * 256 + threadIdx.x;
  if (i < HSLOT) out_hT[i] = (float)g_hbuf[(size_t)TSTEPS * HSLOT + i];
}

// ---------------- host ----------------
extern "C" void kernel_launch(void* const* d_in, const int* in_sizes, int n_in,
                              void* d_out, int out_size, void* d_ws, size_t ws_size,
                              hipStream_t stream) {
  (void)in_sizes; (void)n_in; (void)d_ws; (void)ws_size; (void)out_size;
  const float* x    = (const float*)d_in[0];
  const float* U    = (const float*)d_in[1];
  const float* V    = (const float*)d_in[2];
  const float* bias = (const float*)d_in[3];
  float* out = (float*)d_out;

  float* out_hT = out + (size_t)BS * H * TSTEPS;          // 8388608
  float* out_cT = out_hT + (size_t)BS * H;                // 8421376

  prep_zero<<<dim3(129), dim3(256), 0, stream>>>();
  build_w16t<<<dim3(64, 32), dim3(256), 0, stream>>>(U, V);
  build_xt16<<<dim3(16, 8, 64), dim3(256), 0, stream>>>(x);
  xu_gemm<<<dim3(512, 64), dim3(256), 0, stream>>>(bias);
  lstm_rec<<<dim3(N_BLOCKS), dim3(256), 0, stream>>>(out_cT);
  finalize_seq<<<dim3(16, 8, 64), dim3(256), 0, stream>>>(out);
  copy_hT<<<dim3(128), dim3(256), 0, stream>>>(out_hT);
}